// Round 6
// baseline (253.657 us; speedup 1.0000x reference)
//
#include <hip/hip_runtime.h>

// CoL: out[p] = sum_{q in 3x3} W[q-p] * L[bin(x_q), bin(x_p)] * x_q
// B=32 C=64 H=128 W=128, L is 5x5, zero pad, bin(x)=clamp((int)(x*5),0,4).
//
// R8 design (occupancy fix): R7's long-lived walker kept clean traffic but
// VGPR=128 capped residency at 4 waves/SIMD (measured ~1.6 effective) and
// the LDS gather queue ran half-empty (dur 98.7 vs 44.5us LDS-pipe floor).
// This version cuts live state to ~85 VGPR for 5-6 waves/SIMD:
//  - 1 row/step x 8 steps, rolling 3-row x 10-col window (30 float regs).
//  - Bins stored PACKED: b*20 as 4 bytes/reg, 3 regs/row (9 total vs 30
//    ints); unpacked at use by a single literal-operand BFE per gather.
//    Extra ~144 issue-cyc/step is far below the 44.5us LDS floor.
//  - No prefetch buffers: 3-slot rotation, TLP (from higher occupancy)
//    covers the one L3-hit row load per step.
//  - All slot indices are macro literals (R5 lesson: runtime indices ->
//    scratch, WRITE 339MB). bp4 = b*4 via exact magic ((b20*52429)>>18).
//  - LDS table WL[9][25] = W*L; 25-dword sub-tables span 25 distinct
//    banks, same-address lanes broadcast -> conflict-free (measured 0).

namespace {
constexpr int H  = 128;
constexpr int WD = 128;
constexpr int PLANES = 32 * 64;          // B*C = 2048 blocks (1 per plane)
constexpr int PX = 8;                    // pixels per row per thread
constexpr int THREADS = 256;             // 16 col-strips x 16 row-walkers
}

__global__ __launch_bounds__(THREADS, 5) void col_kernel(
    const float* __restrict__ x, const float* __restrict__ Wf,
    const float* __restrict__ Lf, float* __restrict__ out)
{
    __shared__ float WL[9 * 25];         // WL[(dr*3+dw)*25 + bq*5 + bp]
    const int t = threadIdx.x;
    if (t < 225) WL[t] = Wf[t / 25] * Lf[t % 25];
    __syncthreads();

    const int col0 = (t & 15) * PX;
    const int r0   = (t >> 4) * 8;       // first output row of this walker

    const float* xp = x + (size_t)blockIdx.x * (H * WD);
    float* opb      = out + (size_t)blockIdx.x * (H * WD);
    const char* wlb = (const char*)WL;

    float win[3][PX + 2];                // rolling 3-row window (floats)
    int   pk[3][3];                      // packed bins: b*20 per byte, 4/reg

// ---- all-literal-index helpers (keep mem2reg alive; R5 lesson) ---------
#define LOAD_ROW(S, RR) {                                                 \
    const int _rr = (RR);                                                 \
    if (_rr >= 0 && _rr < H) {                                            \
        const float* _rp = xp + _rr * WD + col0;                          \
        const float4 _c0 = *(const float4*)_rp;      /* 16B aligned */    \
        const float4 _c1 = *(const float4*)(_rp + 4);                     \
        win[S][0] = (col0 > 0) ? _rp[-1] : 0.f;                           \
        win[S][1] = _c0.x; win[S][2] = _c0.y;                             \
        win[S][3] = _c0.z; win[S][4] = _c0.w;                             \
        win[S][5] = _c1.x; win[S][6] = _c1.y;                             \
        win[S][7] = _c1.z; win[S][8] = _c1.w;                             \
        win[S][9] = (col0 < WD - PX) ? _rp[PX] : 0.f;                     \
    } else {                                                              \
        _Pragma("unroll")                                                 \
        for (int _j = 0; _j < PX + 2; ++_j) win[S][_j] = 0.f;             \
    } }

// quantize row S and pack b*20 (0..80) into bytes: 3 regs per row
#define QPACK(S) {                                                        \
    int _b[PX + 2];                                                       \
    _Pragma("unroll")                                                     \
    for (int _j = 0; _j < PX + 2; ++_j) {                                 \
        int _v = (int)(win[S][_j] * 5.0f);    /* x>=0: trunc==floor */    \
        _v = (_v > 4) ? 4 : _v;                                           \
        _b[_j] = _v * 20;                                                 \
    }                                                                     \
    pk[S][0] = _b[0] | (_b[1] << 8) | (_b[2] << 16) | (_b[3] << 24);      \
    pk[S][1] = _b[4] | (_b[5] << 8) | (_b[6] << 16) | (_b[7] << 24);      \
    pk[S][2] = _b[8] | (_b[9] << 8); }

// byte-field extract, S and J are compile-time literals -> one v_bfe
#define BF(S, J) ((pk[S][(J) >> 2] >> (8 * ((J) & 3))) & 0xff)

// 24 gathers + 24 fma for q-row in slot QS at window offset DR
#define TERMS(QS, DR) {                                                   \
    _Pragma("unroll")                                                     \
    for (int _dw = 0; _dw < 3; ++_dw) {                                   \
        float _lw[PX];                                                    \
        _Pragma("unroll")                                                 \
        for (int _i = 0; _i < PX; ++_i)                                   \
            _lw[_i] = *(const float*)(wlb +                               \
                (BF(QS, _i + _dw) + bp4[_i] + ((DR) * 3 + _dw) * 100));   \
        _Pragma("unroll")                                                 \
        for (int _i = 0; _i < PX; ++_i)                                   \
            acc[_i] = fmaf(_lw[_i], win[QS][_i + _dw], acc[_i]);          \
    } }

// one output row R; slots A,B,C hold rows R-1, R, R+1 (B = center)
#define COMPUTE(A, B, C, R) {                                             \
    int bp4[PX];                                                          \
    _Pragma("unroll")                                                     \
    for (int _i = 0; _i < PX; ++_i)                                       \
        bp4[_i] = (BF(B, _i + 1) * 52429) >> 18;    /* b*20 -> b*4 */     \
    float acc[PX];                                                        \
    _Pragma("unroll")                                                     \
    for (int _i = 0; _i < PX; ++_i) acc[_i] = 0.f;                        \
    TERMS(A, 0)                                                           \
    TERMS(B, 1)                                                           \
    TERMS(C, 2)                                                           \
    float* _op = opb + (R) * WD + col0;                                   \
    *(float4*)_op       = make_float4(acc[0], acc[1], acc[2], acc[3]);    \
    *(float4*)(_op + 4) = make_float4(acc[4], acc[5], acc[6], acc[7]);    \
    }

    // ---- prologue: rows r0-1, r0, r0+1 into slots 0,1,2 ---------------
    LOAD_ROW(0, r0 - 1) QPACK(0)
    LOAD_ROW(1, r0 + 0) QPACK(1)
    LOAD_ROW(2, r0 + 1) QPACK(2)

    // ---- 8 steps, slot roles rotate with period 3 ---------------------
    COMPUTE(0, 1, 2, r0 + 0)  LOAD_ROW(0, r0 + 2) QPACK(0)
    COMPUTE(1, 2, 0, r0 + 1)  LOAD_ROW(1, r0 + 3) QPACK(1)
    COMPUTE(2, 0, 1, r0 + 2)  LOAD_ROW(2, r0 + 4) QPACK(2)
    COMPUTE(0, 1, 2, r0 + 3)  LOAD_ROW(0, r0 + 5) QPACK(0)
    COMPUTE(1, 2, 0, r0 + 4)  LOAD_ROW(1, r0 + 6) QPACK(1)
    COMPUTE(2, 0, 1, r0 + 5)  LOAD_ROW(2, r0 + 7) QPACK(2)
    COMPUTE(0, 1, 2, r0 + 6)  LOAD_ROW(0, r0 + 8) QPACK(0)
    COMPUTE(1, 2, 0, r0 + 7)

#undef LOAD_ROW
#undef QPACK
#undef BF
#undef TERMS
#undef COMPUTE
}

extern "C" void kernel_launch(void* const* d_in, const int* in_sizes, int n_in,
                              void* d_out, int out_size, void* d_ws, size_t ws_size,
                              hipStream_t stream) {
    const float* x  = (const float*)d_in[0];   // input_tensor (B,C,H,W) fp32
    const float* Wf = (const float*)d_in[1];   // W (1,3,3) fp32
    const float* Lf = (const float*)d_in[2];   // L (5,5) fp32
    float* out = (float*)d_out;

    col_kernel<<<dim3(PLANES), dim3(THREADS), 0, stream>>>(x, Wf, Lf, out);
}